// Round 1
// 10958.791 us; speedup vs baseline: 1.3642x; 1.3642x over previous
//
#include <hip/hip_runtime.h>

// ManualLSTM round 7: POISON-TAGGED DATA PROTOCOL.
// Delta vs round 6: delete the flag/fence synchronization entirely.
//   - out[B][T][H] is pre-filled with a NaN bit pattern (0x7fc0dead) by a
//     cheap pre-kernel. Computed h (= sigmoid*tanh products) is always finite,
//     so it can never collide with the poison encoding.
//   - Consumers gather h_{t-1} with the same 64-bit agent-scope atomic loads
//     as before, but RETRY until no word is poison. The data word IS the ready
//     flag: no release fence, no flag store, no flag poll, no acquire fence
//     (the per-step buffer_inv also stopped trashing L1 for the x-loads).
//   - Per-word atomicity of the 32-bit halves of a 64-bit load makes the
//     protocol race-free; per-t output slices give natural multi-buffering.

#define B_   32
#define T_   1024
#define I_   512
#define H_   512
#define GB   16     // batches per group
#define CPG  128    // CUs (blocks) per group
#define TILES 8     // K=256 per wave / 32 per MFMA

#define POISON 0x7fc0deadu   // quiet-NaN payload; finite floats never match

typedef __attribute__((ext_vector_type(8))) short short8;
typedef __attribute__((ext_vector_type(4))) float floatx4;

struct Params {
  const float* x;
  const float* h0;
  const float* c0;
  const float* Wi[4];   // W_ii, W_if, W_io, W_ig   [512x512] row-major [k][col]
  const float* Wh[4];   // W_hi, W_hf, W_ho, W_hg
  const float* bias[4]; // b_i, b_f, b_o, b_g
  float* out;           // [32][1024][512] outputs, then h_t [32][512], c_t [32][512]
};

// float -> bf16 bits, round-to-nearest-even (no NaN care needed here)
__device__ __forceinline__ short f2bf(float f) {
  unsigned int x = __builtin_bit_cast(unsigned int, f);
  unsigned int r = (x + 0x7fffu + ((x >> 16) & 1u)) >> 16;
  return (short)r;
}

// Pre-fill the [B][T][H] output region with poison. 16384 blocks x 256 thr x
// 16 B = exactly 32*1024*512 floats.
__global__ void poison_out(float* out) {
  const long i = ((long)blockIdx.x * blockDim.x + threadIdx.x) * 4;
  uint4 v; v.x = POISON; v.y = POISON; v.z = POISON; v.w = POISON;
  *(uint4*)(out + i) = v;
}

__global__ __launch_bounds__(256, 1) void lstm_persistent(Params p) {
  const int tid  = threadIdx.x;
  const int wave = tid >> 6;
  const int lane = tid & 63;
  const int g    = blockIdx.x / CPG;   // batch group (0,1)
  const int c    = blockIdx.x % CPG;   // CU index within group
  const int quad = lane >> 4;
  const int n16  = lane & 15;

  __shared__ float part[2][4][256];    // [parity][wave][16m x 16n] partial C

  // ---- stationary weight B-fragments (bf16). B[k][n]: n = lane&15, k = quad*8+j ----
  short8 bfrag[TILES];
  {
    const int q   = n16 & 3;           // gate: 0=i 1=f 2=o 3=g
    const int u   = n16 >> 2;          // unit within CU
    const int col = c * 4 + u;         // hidden column 0..511
    const float* Wh = p.Wh[q];
    const float* Wi = p.Wi[q];
#pragma unroll
    for (int T = 0; T < TILES; ++T) {
      const int kb = wave * 256 + T * 32 + quad * 8;
      short8 v;
#pragma unroll
      for (int j = 0; j < 8; ++j) {
        const int k = kb + j;          // 0..1023: [h ; x]
        const float w = (k < H_) ? Wh[k * H_ + col] : Wi[(k - H_) * H_ + col];
        v[j] = f2bf(w);
      }
      bfrag[T] = v;
    }
  }

  // ---- epilogue state (wave 0 only): lane l -> (m = l>>2 batch row, u = l&3 unit) ----
  float cst = 0.f;
  float bi0 = 0.f, bi1 = 0.f, bi2 = 0.f, bi3 = 0.f;
  int m_e = 0, jc_e = 0, b_e = 0;
  if (wave == 0) {
    m_e  = lane >> 2;
    const int u_e = lane & 3;
    jc_e = c * 4 + u_e;
    b_e  = g * GB + m_e;
    cst  = p.c0[b_e * H_ + jc_e];
    bi0 = p.bias[0][jc_e]; bi1 = p.bias[1][jc_e];
    bi2 = p.bias[2][jc_e]; bi3 = p.bias[3][jc_e];
  }

  const int mrow = n16;                // A row = batch within group
  const int bA   = g * GB + mrow;
  float* outp = p.out;
  const long HT_OFF = (long)B_ * T_ * H_;
  const long CT_OFF = HT_OFF + (long)B_ * H_;

#pragma unroll 1
  for (int t = 0; t < T_; ++t) {
    short8 afrag[TILES];

    if (wave < 2) {
      // A rows from h_{t-1} (units 0..511); wave0 k 0..255, wave1 k 256..511
      if (t > 0) {
        const float* src = outp + ((long)bA * T_ + (t - 1)) * H_;
        const unsigned long long* qp =
            (const unsigned long long*)(src + wave * 256);
        unsigned long long q[TILES * 4];
        // Poll-gather: reload all 32 qwords until none carries poison.
        // The data word is its own ready flag; no fences needed.
        for (;;) {
#pragma unroll
          for (int T = 0; T < TILES; ++T) {
            const int qb = (T * 32 + quad * 8) >> 1;   // qword index in slice
#pragma unroll
            for (int j2 = 0; j2 < 4; ++j2)
              q[T * 4 + j2] = __hip_atomic_load(qp + qb + j2, __ATOMIC_RELAXED,
                                                __HIP_MEMORY_SCOPE_AGENT);
          }
          bool any_poison = false;
#pragma unroll
          for (int T = 0; T < TILES; ++T)
#pragma unroll
            for (int j2 = 0; j2 < 4; ++j2) {
              const unsigned long long qq = q[T * 4 + j2];
              if ((unsigned int)qq == POISON ||
                  (unsigned int)(qq >> 32) == POISON)
                any_poison = true;
            }
          if (!any_poison) break;
        }
#pragma unroll
        for (int T = 0; T < TILES; ++T) {
          short8 v;
#pragma unroll
          for (int j2 = 0; j2 < 4; ++j2) {
            const unsigned long long qq = q[T * 4 + j2];
            v[2 * j2]     = f2bf(__builtin_bit_cast(float, (unsigned int)qq));
            v[2 * j2 + 1] = f2bf(__builtin_bit_cast(float, (unsigned int)(qq >> 32)));
          }
          afrag[T] = v;
        }
      } else {
        const float* src = p.h0 + bA * H_;
#pragma unroll
        for (int T = 0; T < TILES; ++T) {
          const int kb = wave * 256 + T * 32 + quad * 8;
          short8 v;
#pragma unroll
          for (int j = 0; j < 8; ++j) v[j] = f2bf(src[kb + j]);
          afrag[T] = v;
        }
      }
    } else {
      // A rows from x_t (k 512..1023 -> x idx 0..511), plain cached loads
      const float* src = p.x + ((long)bA * T_ + t) * I_ + (wave - 2) * 256;
#pragma unroll
      for (int T = 0; T < TILES; ++T) {
        const int kb = T * 32 + quad * 8;
        short8 v;
#pragma unroll
        for (int j = 0; j < 8; ++j) v[j] = f2bf(src[kb + j]);
        afrag[T] = v;
      }
    }

    floatx4 acc = {0.f, 0.f, 0.f, 0.f};
#pragma unroll
    for (int T = 0; T < TILES; ++T)
      acc = __builtin_amdgcn_mfma_f32_16x16x32_bf16(afrag[T], bfrag[T], acc, 0, 0, 0);

    // C/D layout: col n = lane&15, row m = quad*4 + r
    const int par = t & 1;
#pragma unroll
    for (int r = 0; r < 4; ++r)
      part[par][wave][(quad * 4 + r) * 16 + n16] = acc[r];

    __syncthreads();

    if (wave == 0) {
      const int u_e = lane & 3;
      float s0 = bi0, s1 = bi1, s2 = bi2, s3 = bi3;
#pragma unroll
      for (int w2 = 0; w2 < 4; ++w2) {
        const int base = m_e * 16 + u_e * 4;
        s0 += part[par][w2][base + 0];
        s1 += part[par][w2][base + 1];
        s2 += part[par][w2][base + 2];
        s3 += part[par][w2][base + 3];
      }
      const float ig = 1.f / (1.f + __expf(-s0));
      const float fg = 1.f / (1.f + __expf(-s1));
      const float og = 1.f / (1.f + __expf(-s2));
      const float gg = 1.f - 2.f / (1.f + __expf(2.f * s3));   // tanh
      cst = fg * cst + ig * gg;
      const float th = 1.f - 2.f / (1.f + __expf(2.f * cst)); // tanh(c)
      const float h  = og * th;

      // The store IS the ready signal (finite value overwrites poison).
      __hip_atomic_store(&outp[((long)b_e * T_ + t) * H_ + jc_e], h,
                         __ATOMIC_RELAXED, __HIP_MEMORY_SCOPE_AGENT);
      if (t == T_ - 1) {
        outp[HT_OFF + b_e * H_ + jc_e] = h;
        outp[CT_OFF + b_e * H_ + jc_e] = cst;
      }
    }
  }
}

extern "C" void kernel_launch(void* const* d_in, const int* in_sizes, int n_in,
                              void* d_out, int out_size, void* d_ws, size_t ws_size,
                              hipStream_t stream) {
  Params prm;
  prm.x  = (const float*)d_in[0];
  prm.h0 = (const float*)d_in[1];
  prm.c0 = (const float*)d_in[2];
  prm.Wi[0] = (const float*)d_in[3];  // W_ii
  prm.Wi[1] = (const float*)d_in[4];  // W_if
  prm.Wi[2] = (const float*)d_in[5];  // W_io
  prm.Wi[3] = (const float*)d_in[6];  // W_ig
  prm.Wh[0] = (const float*)d_in[7];  // W_hi
  prm.Wh[1] = (const float*)d_in[8];  // W_hf
  prm.Wh[2] = (const float*)d_in[9];  // W_ho
  prm.Wh[3] = (const float*)d_in[10]; // W_hg
  prm.bias[0] = (const float*)d_in[11];
  prm.bias[1] = (const float*)d_in[12];
  prm.bias[2] = (const float*)d_in[13];
  prm.bias[3] = (const float*)d_in[14];
  prm.out   = (float*)d_out;

  // Poison the [B][T][H] region: 32*1024*512 floats / (256 thr * 4 floats) = 16384 blocks.
  hipLaunchKernelGGL(poison_out, dim3(16384), dim3(256), 0, stream, prm.out);

  void* args[] = { &prm };
  hipLaunchCooperativeKernel((void*)lstm_persistent, dim3(2 * CPG), dim3(256),
                             args, 0, stream);
}

// Round 5
// 10922.582 us; speedup vs baseline: 1.3687x; 1.0033x over previous
//
#include <hip/hip_runtime.h>

// ManualLSTM round 11: RE-ANCHOR on the passing round-7 kernel.
// The 8x32x4 sync-domain shrink failed NaN twice (rounds 8 and 10) with two
// independent implementations; reverting to the proven 2x128x16 structure.
// Single delta vs round 7 (10.96 ms, passing): s_sleep(4) backoff executed
// ONLY when the poll saw poison. Zero cost on the clean path; cuts the
// poll-round rate ~5-10x while waiting, freeing L3 bandwidth for the
// producers' h-stores that the pollers are waiting on.

#define B_   32
#define T_   1024
#define I_   512
#define H_   512
#define GB   16     // batches per group
#define CPG  128    // CUs (blocks) per group
#define TILES 8     // K=256 per wave / 32 per MFMA

#define POISON 0x7fc0deadu   // quiet-NaN payload; finite floats never match

typedef __attribute__((ext_vector_type(8))) short short8;
typedef __attribute__((ext_vector_type(4))) float floatx4;

struct Params {
  const float* x;
  const float* h0;
  const float* c0;
  const float* Wi[4];   // W_ii, W_if, W_io, W_ig   [512x512] row-major [k][col]
  const float* Wh[4];   // W_hi, W_hf, W_ho, W_hg
  const float* bias[4]; // b_i, b_f, b_o, b_g
  float* out;           // [32][1024][512] outputs, then h_t [32][512], c_t [32][512]
};

// float -> bf16 bits, round-to-nearest-even (no NaN care needed here)
__device__ __forceinline__ short f2bf(float f) {
  unsigned int x = __builtin_bit_cast(unsigned int, f);
  unsigned int r = (x + 0x7fffu + ((x >> 16) & 1u)) >> 16;
  return (short)r;
}

// Pre-fill the [B][T][H] output region with poison.
__global__ void poison_out(float* out) {
  const long i = ((long)blockIdx.x * blockDim.x + threadIdx.x) * 4;
  uint4 v; v.x = POISON; v.y = POISON; v.z = POISON; v.w = POISON;
  *(uint4*)(out + i) = v;
}

__global__ __launch_bounds__(256, 1) void lstm_persistent(Params p) {
  const int tid  = threadIdx.x;
  const int wave = tid >> 6;
  const int lane = tid & 63;
  const int g    = blockIdx.x / CPG;   // batch group (0,1)
  const int c    = blockIdx.x % CPG;   // CU index within group
  const int quad = lane >> 4;
  const int n16  = lane & 15;

  __shared__ float part[2][4][256];    // [parity][wave][16m x 16n] partial C

  // ---- stationary weight B-fragments (bf16). B[k][n]: n = lane&15, k = quad*8+j ----
  short8 bfrag[TILES];
  {
    const int q   = n16 & 3;           // gate: 0=i 1=f 2=o 3=g
    const int u   = n16 >> 2;          // unit within CU
    const int col = c * 4 + u;         // hidden column 0..511
    const float* Wh = p.Wh[q];
    const float* Wi = p.Wi[q];
#pragma unroll
    for (int T = 0; T < TILES; ++T) {
      const int kb = wave * 256 + T * 32 + quad * 8;
      short8 v;
#pragma unroll
      for (int j = 0; j < 8; ++j) {
        const int k = kb + j;          // 0..1023: [h ; x]
        const float w = (k < H_) ? Wh[k * H_ + col] : Wi[(k - H_) * H_ + col];
        v[j] = f2bf(w);
      }
      bfrag[T] = v;
    }
  }

  // ---- epilogue state (wave 0 only): lane l -> (m = l>>2 batch row, u = l&3 unit) ----
  float cst = 0.f;
  float bi0 = 0.f, bi1 = 0.f, bi2 = 0.f, bi3 = 0.f;
  int m_e = 0, jc_e = 0, b_e = 0;
  if (wave == 0) {
    m_e  = lane >> 2;
    const int u_e = lane & 3;
    jc_e = c * 4 + u_e;
    b_e  = g * GB + m_e;
    cst  = p.c0[b_e * H_ + jc_e];
    bi0 = p.bias[0][jc_e]; bi1 = p.bias[1][jc_e];
    bi2 = p.bias[2][jc_e]; bi3 = p.bias[3][jc_e];
  }

  const int mrow = n16;                // A row = batch within group
  const int bA   = g * GB + mrow;
  float* outp = p.out;
  const long HT_OFF = (long)B_ * T_ * H_;
  const long CT_OFF = HT_OFF + (long)B_ * H_;

#pragma unroll 1
  for (int t = 0; t < T_; ++t) {
    short8 afrag[TILES];

    if (wave < 2) {
      // A rows from h_{t-1} (units 0..511); wave0 k 0..255, wave1 k 256..511
      if (t > 0) {
        const float* src = outp + ((long)bA * T_ + (t - 1)) * H_;
        const unsigned long long* qp =
            (const unsigned long long*)(src + wave * 256);
        unsigned long long q[TILES * 4];
        // Poll-gather: reload all 32 qwords until none carries poison.
        // The data word is its own ready flag; no fences needed.
        for (;;) {
#pragma unroll
          for (int T = 0; T < TILES; ++T) {
            const int qb = (T * 32 + quad * 8) >> 1;   // qword index in slice
#pragma unroll
            for (int j2 = 0; j2 < 4; ++j2)
              q[T * 4 + j2] = __hip_atomic_load(qp + qb + j2, __ATOMIC_RELAXED,
                                                __HIP_MEMORY_SCOPE_AGENT);
          }
          bool any_poison = false;
#pragma unroll
          for (int T = 0; T < TILES; ++T)
#pragma unroll
            for (int j2 = 0; j2 < 4; ++j2) {
              const unsigned long long qq = q[T * 4 + j2];
              if ((unsigned int)qq == POISON ||
                  (unsigned int)(qq >> 32) == POISON)
                any_poison = true;
            }
          if (!any_poison) break;
          // Backoff ~256 cycles: only reached when data wasn't ready.
          __builtin_amdgcn_s_sleep(4);
        }
#pragma unroll
        for (int T = 0; T < TILES; ++T) {
          short8 v;
#pragma unroll
          for (int j2 = 0; j2 < 4; ++j2) {
            const unsigned long long qq = q[T * 4 + j2];
            v[2 * j2]     = f2bf(__builtin_bit_cast(float, (unsigned int)qq));
            v[2 * j2 + 1] = f2bf(__builtin_bit_cast(float, (unsigned int)(qq >> 32)));
          }
          afrag[T] = v;
        }
      } else {
        const float* src = p.h0 + bA * H_;
#pragma unroll
        for (int T = 0; T < TILES; ++T) {
          const int kb = wave * 256 + T * 32 + quad * 8;
          short8 v;
#pragma unroll
          for (int j = 0; j < 8; ++j) v[j] = f2bf(src[kb + j]);
          afrag[T] = v;
        }
      }
    } else {
      // A rows from x_t (k 512..1023 -> x idx 0..511), plain cached loads
      const float* src = p.x + ((long)bA * T_ + t) * I_ + (wave - 2) * 256;
#pragma unroll
      for (int T = 0; T < TILES; ++T) {
        const int kb = T * 32 + quad * 8;
        short8 v;
#pragma unroll
        for (int j = 0; j < 8; ++j) v[j] = f2bf(src[kb + j]);
        afrag[T] = v;
      }
    }

    floatx4 acc = {0.f, 0.f, 0.f, 0.f};
#pragma unroll
    for (int T = 0; T < TILES; ++T)
      acc = __builtin_amdgcn_mfma_f32_16x16x32_bf16(afrag[T], bfrag[T], acc, 0, 0, 0);

    // C/D layout: col n = lane&15, row m = quad*4 + r
    const int par = t & 1;
#pragma unroll
    for (int r = 0; r < 4; ++r)
      part[par][wave][(quad * 4 + r) * 16 + n16] = acc[r];

    __syncthreads();

    if (wave == 0) {
      const int u_e = lane & 3;
      float s0 = bi0, s1 = bi1, s2 = bi2, s3 = bi3;
#pragma unroll
      for (int w2 = 0; w2 < 4; ++w2) {
        const int base = m_e * 16 + u_e * 4;
        s0 += part[par][w2][base + 0];
        s1 += part[par][w2][base + 1];
        s2 += part[par][w2][base + 2];
        s3 += part[par][w2][base + 3];
      }
      const float ig = 1.f / (1.f + __expf(-s0));
      const float fg = 1.f / (1.f + __expf(-s1));
      const float og = 1.f / (1.f + __expf(-s2));
      const float gg = 1.f - 2.f / (1.f + __expf(2.f * s3));   // tanh
      cst = fg * cst + ig * gg;
      const float th = 1.f - 2.f / (1.f + __expf(2.f * cst)); // tanh(c)
      const float h  = og * th;

      // The store IS the ready signal (finite value overwrites poison).
      __hip_atomic_store(&outp[((long)b_e * T_ + t) * H_ + jc_e], h,
                         __ATOMIC_RELAXED, __HIP_MEMORY_SCOPE_AGENT);
      if (t == T_ - 1) {
        outp[HT_OFF + b_e * H_ + jc_e] = h;
        outp[CT_OFF + b_e * H_ + jc_e] = cst;
      }
    }
  }
}

extern "C" void kernel_launch(void* const* d_in, const int* in_sizes, int n_in,
                              void* d_out, int out_size, void* d_ws, size_t ws_size,
                              hipStream_t stream) {
  Params prm;
  prm.x  = (const float*)d_in[0];
  prm.h0 = (const float*)d_in[1];
  prm.c0 = (const float*)d_in[2];
  prm.Wi[0] = (const float*)d_in[3];  // W_ii
  prm.Wi[1] = (const float*)d_in[4];  // W_if
  prm.Wi[2] = (const float*)d_in[5];  // W_io
  prm.Wi[3] = (const float*)d_in[6];  // W_ig
  prm.Wh[0] = (const float*)d_in[7];  // W_hi
  prm.Wh[1] = (const float*)d_in[8];  // W_hf
  prm.Wh[2] = (const float*)d_in[9];  // W_ho
  prm.Wh[3] = (const float*)d_in[10]; // W_hg
  prm.bias[0] = (const float*)d_in[11];
  prm.bias[1] = (const float*)d_in[12];
  prm.bias[2] = (const float*)d_in[13];
  prm.bias[3] = (const float*)d_in[14];
  prm.out   = (float*)d_out;

  // Poison the [B][T][H] region: 32*1024*512 floats / (256 thr * 4 floats).
  hipLaunchKernelGGL(poison_out, dim3(16384), dim3(256), 0, stream, prm.out);

  void* args[] = { &prm };
  hipLaunchCooperativeKernel((void*)lstm_persistent, dim3(2 * CPG), dim3(256),
                             args, 0, stream);
}